// Round 3
// baseline (2577.644 us; speedup 1.0000x reference)
//
#include <hip/hip_runtime.h>
#include <hip/hip_bf16.h>
#include <math.h>

#define S_LEN 256
#define B 32
#define E 512
#define H 512
#define G4 2048          // 4*H
#define T_TAGS 30
#define START_TAG 28
#define STOP_TAG 29

typedef unsigned short u16;
typedef unsigned int   u32;
typedef __attribute__((ext_vector_type(8))) short bf16x8;
typedef __attribute__((ext_vector_type(4))) float f32x4;

__device__ __forceinline__ float bf2f(u16 u){
  u32 x = ((u32)u) << 16;
  return __uint_as_float(x);
}
__device__ __forceinline__ u16 f2bf(float f){
  u32 x = __float_as_uint(f);
  u32 r = (x + 0x7fffu + ((x >> 16) & 1u)) >> 16;
  return (u16)r;
}
__device__ __forceinline__ float sigf(float x){
  return 1.0f / (1.0f + __expf(-x));
}
__device__ __forceinline__ float tanh_fast(float x){
  return 1.0f - 2.0f / (__expf(2.0f * x) + 1.0f);
}

// ---------------- prep: gather + f32->bf16 for A (emb rows) ----------------
__global__ __launch_bounds__(256) void k_prep_a(
    const int* __restrict__ sent, const float* __restrict__ emb,
    u16* __restrict__ a16)
{
  int g = (blockIdx.x * 256 + threadIdx.x) * 8;      // < 8192*512
  int token = g >> 9, k = g & 511;
  const float* src = emb + (size_t)sent[token] * E + k;
  float4 v0 = *reinterpret_cast<const float4*>(src);
  float4 v1 = *reinterpret_cast<const float4*>(src + 4);
  u16 o[8];
  o[0]=f2bf(v0.x); o[1]=f2bf(v0.y); o[2]=f2bf(v0.z); o[3]=f2bf(v0.w);
  o[4]=f2bf(v1.x); o[5]=f2bf(v1.y); o[6]=f2bf(v1.z); o[7]=f2bf(v1.w);
  *reinterpret_cast<uint4*>(a16 + g) = *reinterpret_cast<const uint4*>(o);
}

// ---------------- prep: generic f32 -> bf16 ----------------
__global__ __launch_bounds__(256) void k_cvt(const float* __restrict__ src, u16* __restrict__ dst){
  int g = (blockIdx.x * 256 + threadIdx.x) * 8;
  float4 v0 = *reinterpret_cast<const float4*>(src + g);
  float4 v1 = *reinterpret_cast<const float4*>(src + g + 4);
  u16 o[8];
  o[0]=f2bf(v0.x); o[1]=f2bf(v0.y); o[2]=f2bf(v0.z); o[3]=f2bf(v0.w);
  o[4]=f2bf(v1.x); o[5]=f2bf(v1.y); o[6]=f2bf(v1.z); o[7]=f2bf(v1.w);
  *reinterpret_cast<uint4*>(dst + g) = *reinterpret_cast<const uint4*>(o);
}

// ---------------- init: h0 -> bf16 parity0, zero barrier counters ----------------
__global__ __launch_bounds__(256) void k_init16(
    const float* __restrict__ h0, u16* __restrict__ h16, u32* __restrict__ bar)
{
  int g = (blockIdx.x * 256 + threadIdx.x) * 8;      // < 2*B*H = 32768
  float4 v0 = *reinterpret_cast<const float4*>(h0 + g);
  float4 v1 = *reinterpret_cast<const float4*>(h0 + g + 4);
  u16 o[8];
  o[0]=f2bf(v0.x); o[1]=f2bf(v0.y); o[2]=f2bf(v0.z); o[3]=f2bf(v0.w);
  o[4]=f2bf(v1.x); o[5]=f2bf(v1.y); o[6]=f2bf(v1.z); o[7]=f2bf(v1.w);
  *reinterpret_cast<uint4*>(h16 + g) = *reinterpret_cast<const uint4*>(o);
  if (blockIdx.x == 0 && threadIdx.x < 2) bar[threadIdx.x] = 0u;
}

// ---------------- phase A: xw = A16 @ W16^T + bias  (bf16 MFMA, 128x128 tile) ----------------
__global__ __launch_bounds__(256) void k_gemm_xw16(
    const u16* __restrict__ a16, const u16* __restrict__ w16ih,
    const float* __restrict__ b_ih_f, const float* __restrict__ b_hh_f,
    const float* __restrict__ b_ih_b, const float* __restrict__ b_hh_b,
    u16* __restrict__ xw)
{
  int dir = blockIdx.z;
  int n0 = blockIdx.x * 128;
  int m0 = blockIdx.y * 128;
  const u16* Wp = w16ih + (size_t)dir * G4 * E;
  const float* bi = dir ? b_ih_b : b_ih_f;
  const float* bh = dir ? b_hh_b : b_hh_f;
  int tid = threadIdx.x;

  __shared__ u16 As[128 * 32];
  __shared__ u16 Bs[128 * 32];

  int l  = tid & 63;
  int wid = tid >> 6;
  int wr = wid >> 1, wc = wid & 1;       // 2x2 wave grid, each wave 64x64
  int lr = l & 15, lh = l >> 4;
  int swzr = (lh ^ (lr & 3)) << 3;

  f32x4 acc[4][4];
  #pragma unroll
  for (int i = 0; i < 4; ++i)
    #pragma unroll
    for (int j = 0; j < 4; ++j)
      acc[i][j] = (f32x4){0.f, 0.f, 0.f, 0.f};

  for (int kt = 0; kt < E; kt += 32){
    __syncthreads();
    #pragma unroll
    for (int it = 0; it < 2; ++it){
      int u = it * 256 + tid;            // 0..511 (16B units)
      int row = u >> 2, c = u & 3;
      int sw = (c ^ (row & 3)) << 3;
      *reinterpret_cast<uint4*>(&As[row * 32 + sw]) =
        *reinterpret_cast<const uint4*>(a16 + (size_t)(m0 + row) * E + kt + c * 8);
      *reinterpret_cast<uint4*>(&Bs[row * 32 + sw]) =
        *reinterpret_cast<const uint4*>(Wp + (size_t)(n0 + row) * E + kt + c * 8);
    }
    __syncthreads();
    bf16x8 a[4], b[4];
    #pragma unroll
    for (int mi = 0; mi < 4; ++mi)
      a[mi] = *reinterpret_cast<const bf16x8*>(&As[(wr * 64 + mi * 16 + lr) * 32 + swzr]);
    #pragma unroll
    for (int ni = 0; ni < 4; ++ni)
      b[ni] = *reinterpret_cast<const bf16x8*>(&Bs[(wc * 64 + ni * 16 + lr) * 32 + swzr]);
    #pragma unroll
    for (int mi = 0; mi < 4; ++mi)
      #pragma unroll
      for (int ni = 0; ni < 4; ++ni)
        acc[mi][ni] = __builtin_amdgcn_mfma_f32_16x16x32_bf16(a[mi], b[ni], acc[mi][ni], 0, 0, 0);
  }

  #pragma unroll
  for (int ni = 0; ni < 4; ++ni){
    int n = n0 + wc * 64 + ni * 16 + lr;
    float bias = bi[n] + bh[n];
    #pragma unroll
    for (int mi = 0; mi < 4; ++mi){
      #pragma unroll
      for (int r = 0; r < 4; ++r){
        int m = m0 + wr * 64 + mi * 16 + lh * 4 + r;
        xw[((size_t)dir * 8192 + m) * G4 + n] = f2bf(acc[mi][ni][r] + bias);
      }
    }
  }
}

// ---------------- persistent bidirectional LSTM recurrence ----------------
// 64 blocks: dir = bx>>5 (32 blocks per dir), j0 = (bx&31)*16 (16 h-dims per block).
// Per block: w_hh slice (4 gates x 16 j x 512) resident in LDS; c in registers;
// h broadcast via global double-buffer; per-dir monotonic-counter grid barrier.
__device__ __forceinline__ void grid_bar(u32* cnt, u32 target){
  __syncthreads();
  if (threadIdx.x == 0){
    __threadfence();
    __hip_atomic_fetch_add(cnt, 1u, __ATOMIC_RELEASE, __HIP_MEMORY_SCOPE_AGENT);
    while (__hip_atomic_load(cnt, __ATOMIC_ACQUIRE, __HIP_MEMORY_SCOPE_AGENT) < target)
      __builtin_amdgcn_s_sleep(2);
    __threadfence();
  }
  __syncthreads();
}

__global__ __launch_bounds__(256) void k_lstm_all(
    const u16* __restrict__ w16hh, const u16* __restrict__ xw,
    u16* __restrict__ h16,              // [2 parity][2 dir][32][512] bf16
    const float* __restrict__ c0,       // [2][32][512] f32
    u16* __restrict__ hseq,             // [2 dir][8192][512] bf16
    u32* __restrict__ bar)              // [2] per-dir counters (zeroed each launch)
{
  __shared__ u16   w_s[64 * 512];       // 64 KB, XOR-swizzled
  __shared__ float gate_s[4][32][17];   // [gate][batch][jj]

  int bx  = blockIdx.x;
  int dir = bx >> 5;
  int j0  = (bx & 31) << 4;
  int tid = threadIdx.x;

  // ---- stage w_hh slice into LDS once (rows r = g*16+jj -> global row g*512+j0+jj) ----
  #pragma unroll
  for (int i = 0; i < 16; ++i){
    int u = i * 256 + tid;              // 0..4095 (16B units)
    int r = u >> 6, ku = u & 63;
    int g = r >> 4, jj = r & 15;
    const u16* src = w16hh + (size_t)dir * (G4 * H) + (size_t)((g << 9) + j0 + jj) * H + ku * 8;
    int idx = (r * 512 + ku * 8) ^ ((r & 7) << 3);
    *reinterpret_cast<uint4*>(&w_s[idx]) = *reinterpret_cast<const uint4*>(src);
  }

  int l  = tid & 63;
  int wid = tid >> 6;
  int wr = wid >> 1;                    // batch half (0,1)
  int wc = wid & 1;                     // gate pair (0: i,f  1: g,o)
  int lr = l & 15, lh = l >> 4;

  int r0 = wc * 32 + lr;                // W_lds row for gate 2*wc
  int r1 = r0 + 16;                     // gate 2*wc+1
  int base0 = r0 * 512 + lh * 8;
  int base1 = r1 * 512 + lh * 8;
  int sw = (lr & 7) << 3;               // (r0&7)==(r1&7)==(lr&7)

  // epilogue mapping: thread -> (batch eb, 2 adjacent jj)
  int eb = tid >> 3;
  int ej = (tid & 7) << 1;
  float c_reg[2];
  c_reg[0] = c0[((size_t)dir * B + eb) * H + j0 + ej];
  c_reg[1] = c0[((size_t)dir * B + eb) * H + j0 + ej + 1];

  __syncthreads();

  for (int t = 0; t < S_LEN; ++t){
    int s_eff = dir ? (S_LEN - 1 - t) : t;

    // prefetch xw for the epilogue (independent of h)
    const u16* xwp = xw + ((size_t)dir * 8192 + (size_t)s_eff * B + eb) * G4 + j0 + ej;
    u32 xi = *reinterpret_cast<const u32*>(xwp);
    u32 xf = *reinterpret_cast<const u32*>(xwp + 512);
    u32 xg = *reinterpret_cast<const u32*>(xwp + 1024);
    u32 xo = *reinterpret_cast<const u32*>(xwp + 1536);

    // gates = h @ W^T for this block's 64 gate-rows
    const u16* ap = h16 + (size_t)(t & 1) * (2 * B * H) + (size_t)dir * (B * H)
                  + (size_t)((wr << 4) + lr) * H + (lh << 3);
    f32x4 acc0 = {0.f,0.f,0.f,0.f}, acc1 = {0.f,0.f,0.f,0.f};
    #pragma unroll
    for (int kt = 0; kt < 16; ++kt){
      bf16x8 a  = *reinterpret_cast<const bf16x8*>(ap + kt * 32);
      bf16x8 b0 = *reinterpret_cast<const bf16x8*>(&w_s[(base0 + kt * 32) ^ sw]);
      bf16x8 b1 = *reinterpret_cast<const bf16x8*>(&w_s[(base1 + kt * 32) ^ sw]);
      acc0 = __builtin_amdgcn_mfma_f32_16x16x32_bf16(a, b0, acc0, 0, 0, 0);
      acc1 = __builtin_amdgcn_mfma_f32_16x16x32_bf16(a, b1, acc1, 0, 0, 0);
    }
    #pragma unroll
    for (int r = 0; r < 4; ++r){
      gate_s[wc * 2 + 0][(wr << 4) + (lh << 2) + r][lr] = acc0[r];
      gate_s[wc * 2 + 1][(wr << 4) + (lh << 2) + r][lr] = acc1[r];
    }
    __syncthreads();

    // epilogue: c/h update for (eb, ej..ej+1)
    float hv[2];
    #pragma unroll
    for (int e = 0; e < 2; ++e){
      float iv = gate_s[0][eb][ej + e] + bf2f(e ? (u16)(xi >> 16) : (u16)(xi & 0xffff));
      float fv = gate_s[1][eb][ej + e] + bf2f(e ? (u16)(xf >> 16) : (u16)(xf & 0xffff));
      float gv = gate_s[2][eb][ej + e] + bf2f(e ? (u16)(xg >> 16) : (u16)(xg & 0xffff));
      float ov = gate_s[3][eb][ej + e] + bf2f(e ? (u16)(xo >> 16) : (u16)(xo & 0xffff));
      float cn = sigf(fv) * c_reg[e] + sigf(iv) * tanh_fast(gv);
      hv[e] = sigf(ov) * tanh_fast(cn);
      c_reg[e] = cn;
    }
    u32 hpack = (u32)f2bf(hv[0]) | ((u32)f2bf(hv[1]) << 16);
    size_t hoff = ((size_t)dir * B + eb) * H + j0 + ej;
    *reinterpret_cast<u32*>(reinterpret_cast<char*>(h16) +
        ((size_t)((t + 1) & 1) * (2 * B * H) + hoff) * 2) = hpack;
    *reinterpret_cast<u32*>(hseq + ((size_t)dir * 8192 + (size_t)s_eff * B + eb) * H + j0 + ej) = hpack;

    if (t < S_LEN - 1)
      grid_bar(&bar[dir], 32u * (u32)(t + 1));
  }
}

// ---------------- phase C: feats[b][s][t] = [hf;hb] . w_out[t] + b_out[t] ----------------
__global__ __launch_bounds__(256) void k_feats2(
    const u16* __restrict__ hseq, const float* __restrict__ w_out,
    const float* __restrict__ b_out, float* __restrict__ feats)
{
  __shared__ float row[32][1028];
  int blk = blockIdx.x;
  int tid = threadIdx.x;
  const u16* hf16 = hseq;
  const u16* hb16 = hseq + (size_t)8192 * H;

  #pragma unroll
  for (int it = 0; it < 16; ++it){
    int u = it * 256 + tid;
    int flat = u * 8;
    int i = flat >> 10, d = flat & 1023;
    int m = blk * 32 + i;
    const u16* src = (d < 512) ? (hf16 + (size_t)m * H + d) : (hb16 + (size_t)m * H + d - 512);
    uint4 v = *reinterpret_cast<const uint4*>(src);
    float* dst = &row[i][d];
    dst[0] = bf2f((u16)(v.x & 0xffff)); dst[1] = bf2f((u16)(v.x >> 16));
    dst[2] = bf2f((u16)(v.y & 0xffff)); dst[3] = bf2f((u16)(v.y >> 16));
    dst[4] = bf2f((u16)(v.z & 0xffff)); dst[5] = bf2f((u16)(v.z >> 16));
    dst[6] = bf2f((u16)(v.w & 0xffff)); dst[7] = bf2f((u16)(v.w >> 16));
  }
  __syncthreads();

  int i = tid >> 3, tg = tid & 7;
  const float* w0 = w_out + (size_t)((tg + 0  < T_TAGS) ? tg + 0  : 0) * 1024;
  const float* w1 = w_out + (size_t)((tg + 8  < T_TAGS) ? tg + 8  : 0) * 1024;
  const float* w2 = w_out + (size_t)((tg + 16 < T_TAGS) ? tg + 16 : 0) * 1024;
  const float* w3 = w_out + (size_t)((tg + 24 < T_TAGS) ? tg + 24 : 0) * 1024;
  float s0 = 0.f, s1 = 0.f, s2 = 0.f, s3 = 0.f;
  #pragma unroll 4
  for (int k4 = 0; k4 < 256; ++k4){
    float4 rv = *reinterpret_cast<const float4*>(&row[i][k4 * 4]);
    float4 a = *reinterpret_cast<const float4*>(w0 + k4 * 4);
    float4 b = *reinterpret_cast<const float4*>(w1 + k4 * 4);
    float4 c = *reinterpret_cast<const float4*>(w2 + k4 * 4);
    float4 d = *reinterpret_cast<const float4*>(w3 + k4 * 4);
    s0 = fmaf(a.x,rv.x,s0); s0 = fmaf(a.y,rv.y,s0); s0 = fmaf(a.z,rv.z,s0); s0 = fmaf(a.w,rv.w,s0);
    s1 = fmaf(b.x,rv.x,s1); s1 = fmaf(b.y,rv.y,s1); s1 = fmaf(b.z,rv.z,s1); s1 = fmaf(b.w,rv.w,s1);
    s2 = fmaf(c.x,rv.x,s2); s2 = fmaf(c.y,rv.y,s2); s2 = fmaf(c.z,rv.z,s2); s2 = fmaf(c.w,rv.w,s2);
    s3 = fmaf(d.x,rv.x,s3); s3 = fmaf(d.y,rv.y,s3); s3 = fmaf(d.z,rv.z,s3); s3 = fmaf(d.w,rv.w,s3);
  }
  int m = blk * 32 + i;
  int s = m >> 5, b = m & 31;
  float* fp = feats + ((size_t)b * S_LEN + s) * T_TAGS;
  float sums[4] = {s0, s1, s2, s3};
  #pragma unroll
  for (int q = 0; q < 4; ++q){
    int tt = tg + q * 8;
    if (tt < T_TAGS) fp[tt] = sums[q] + b_out[tt];
  }
}

// ---------------- phase D: CRF, one wave per batch element, register-resident ----------------
__global__ __launch_bounds__(64) void k_crf2(
    const float* __restrict__ feats, const float* __restrict__ trans,
    const int* __restrict__ tags, float* __restrict__ scores)
{
  int b = blockIdx.x;
  int l = threadIdx.x;

  float trr[T_TAGS];
  #pragma unroll
  for (int j = 0; j < T_TAGS; ++j)
    trr[j] = (l < T_TAGS) ? trans[l * T_TAGS + j] : -1e30f;

  float fv = (l == START_TAG) ? 0.f : -10000.f;
  const float* fb = feats + (size_t)b * S_LEN * T_TAGS;

  for (int s = 0; s < S_LEN; ++s){
    float feat = (l < T_TAGS) ? fb[s * T_TAGS + l] : 0.f;
    float v[T_TAGS];
    float m = -1e30f;
    #pragma unroll
    for (int j = 0; j < T_TAGS; ++j){
      float fvj = __shfl(fv, j);
      v[j] = fvj + trr[j];
      m = fmaxf(m, v[j]);
    }
    float sum = 0.f;
    #pragma unroll
    for (int j = 0; j < T_TAGS; ++j) sum += __expf(v[j] - m);
    fv = feat + m + __logf(sum);
  }

  // forward score: LSE over i<30 of fv[i] + trans[STOP][i]
  float fin = (l < T_TAGS) ? fv + trans[STOP_TAG * T_TAGS + l] : -1e30f;
  float mm = fin;
  #pragma unroll
  for (int o = 32; o > 0; o >>= 1) mm = fmaxf(mm, __shfl_xor(mm, o));
  float e = (l < T_TAGS) ? __expf(fin - mm) : 0.f;
  #pragma unroll
  for (int o = 32; o > 0; o >>= 1) e += __shfl_xor(e, o);
  float fsc = mm + __logf(e);

  // gold score
  float g = 0.f;
  #pragma unroll
  for (int it = 0; it < 4; ++it){
    int s = it * 64 + l;
    int nxt = tags[s * B + b];
    int prv = s ? tags[(s - 1) * B + b] : START_TAG;
    g += trans[nxt * T_TAGS + prv] + fb[s * T_TAGS + nxt];
  }
  #pragma unroll
  for (int o = 32; o > 0; o >>= 1) g += __shfl_down(g, o);
  if (l == 0){
    int last = tags[(S_LEN - 1) * B + b];
    g += trans[STOP_TAG * T_TAGS + last];
    scores[b] = fsc - g;
  }
}

__global__ void k_final(const float* __restrict__ scores, float* __restrict__ out){
  int tid = threadIdx.x;
  float v = (tid < B) ? scores[tid] : 0.f;
  #pragma unroll
  for (int o = 32; o > 0; o >>= 1) v += __shfl_down(v, o);
  if (tid == 0) out[0] = v;
}

// ---------------- host ----------------
extern "C" void kernel_launch(void* const* d_in, const int* in_sizes, int n_in,
                              void* d_out, int out_size, void* d_ws, size_t ws_size,
                              hipStream_t stream)
{
  const int*   sent   = (const int*)d_in[0];
  const int*   tags   = (const int*)d_in[1];
  const float* emb    = (const float*)d_in[2];
  const float* w_ih_f = (const float*)d_in[3];
  const float* w_hh_f = (const float*)d_in[4];
  const float* b_ih_f = (const float*)d_in[5];
  const float* b_hh_f = (const float*)d_in[6];
  const float* w_ih_b = (const float*)d_in[7];
  const float* w_hh_b = (const float*)d_in[8];
  const float* b_ih_b = (const float*)d_in[9];
  const float* b_hh_b = (const float*)d_in[10];
  const float* w_out  = (const float*)d_in[11];
  const float* b_out  = (const float*)d_in[12];
  const float* trans  = (const float*)d_in[13];
  const float* h0     = (const float*)d_in[14];
  const float* c0     = (const float*)d_in[15];

  // ws layout (bytes)
  const size_t OFF_XW   = 0;            // bf16 [2][8192][2048] = 64 MiB
  const size_t OFF_A16  = 67108864;     // bf16 [8192][512]     = 8 MiB
  const size_t OFF_WIH  = 75497472;     // bf16 [2][2048][512]  = 4 MiB
  const size_t OFF_WHH  = 79691776;     // bf16 [2][2048][512]  = 4 MiB
  const size_t OFF_HSEQ = 83886080;     // bf16 [2][8192][512]  = 16 MiB
  const size_t OFF_H16  = 100663296;    // bf16 [2 parity][2][32][512] = 128 KiB
  const size_t OFF_FEATS= 100794368;    // f32  [32][256][30]   = 960 KiB
  const size_t OFF_SC   = 101777408;    // f32  [32]
  const size_t OFF_BAR  = 101777536;    // u32  [2]
  const size_t NEED     = 101777664;
  if (ws_size < NEED) return;

  char* ws = (char*)d_ws;
  u16*   xw     = (u16*)(ws + OFF_XW);
  u16*   a16    = (u16*)(ws + OFF_A16);
  u16*   w16ih  = (u16*)(ws + OFF_WIH);
  u16*   w16hh  = (u16*)(ws + OFF_WHH);
  u16*   hseq   = (u16*)(ws + OFF_HSEQ);
  u16*   h16    = (u16*)(ws + OFF_H16);
  float* feats  = (float*)(ws + OFF_FEATS);
  float* scores = (float*)(ws + OFF_SC);
  u32*   bar    = (u32*)(ws + OFF_BAR);

  k_prep_a<<<2048, 256, 0, stream>>>(sent, emb, a16);
  k_cvt<<<512, 256, 0, stream>>>(w_ih_f, w16ih);
  k_cvt<<<512, 256, 0, stream>>>(w_ih_b, w16ih + (size_t)G4 * E);
  k_cvt<<<512, 256, 0, stream>>>(w_hh_f, w16hh);
  k_cvt<<<512, 256, 0, stream>>>(w_hh_b, w16hh + (size_t)G4 * H);
  k_init16<<<16, 256, 0, stream>>>(h0, h16, bar);

  k_gemm_xw16<<<dim3(G4 / 128, 8192 / 128, 2), 256, 0, stream>>>(
      a16, w16ih, b_ih_f, b_hh_f, b_ih_b, b_hh_b, xw);

  k_lstm_all<<<64, 256, 0, stream>>>(w16hh, xw, h16, c0, hseq, bar);

  k_feats2<<<256, 256, 0, stream>>>(hseq, w_out, b_out, feats);
  k_crf2<<<B, 64, 0, stream>>>(feats, trans, tags, scores);
  k_final<<<1, 64, 0, stream>>>(scores, (float*)d_out);
}

// Round 4
// 2053.674 us; speedup vs baseline: 1.2551x; 1.2551x over previous
//
#include <hip/hip_runtime.h>
#include <hip/hip_bf16.h>
#include <math.h>

#define S_LEN 256
#define B 32
#define E 512
#define H 512
#define G4 2048          // 4*H
#define T_TAGS 30
#define START_TAG 28
#define STOP_TAG 29

typedef unsigned short u16;
typedef unsigned int   u32;
typedef unsigned long long u64;
typedef __attribute__((ext_vector_type(8))) short bf16x8;
typedef __attribute__((ext_vector_type(4))) float f32x4;

__device__ __forceinline__ float bf2f(u16 u){
  u32 x = ((u32)u) << 16;
  return __uint_as_float(x);
}
__device__ __forceinline__ u16 f2bf(float f){
  u32 x = __float_as_uint(f);
  u32 r = (x + 0x7fffu + ((x >> 16) & 1u)) >> 16;
  return (u16)r;
}
__device__ __forceinline__ float sigf(float x){
  return 1.0f / (1.0f + __expf(-x));
}
__device__ __forceinline__ float tanh_fast(float x){
  return 1.0f - 2.0f / (__expf(2.0f * x) + 1.0f);
}

// ---------------- prep: gather + f32->bf16 for A (emb rows) ----------------
__global__ __launch_bounds__(256) void k_prep_a(
    const int* __restrict__ sent, const float* __restrict__ emb,
    u16* __restrict__ a16)
{
  int g = (blockIdx.x * 256 + threadIdx.x) * 8;      // < 8192*512
  int token = g >> 9, k = g & 511;
  const float* src = emb + (size_t)sent[token] * E + k;
  float4 v0 = *reinterpret_cast<const float4*>(src);
  float4 v1 = *reinterpret_cast<const float4*>(src + 4);
  u16 o[8];
  o[0]=f2bf(v0.x); o[1]=f2bf(v0.y); o[2]=f2bf(v0.z); o[3]=f2bf(v0.w);
  o[4]=f2bf(v1.x); o[5]=f2bf(v1.y); o[6]=f2bf(v1.z); o[7]=f2bf(v1.w);
  *reinterpret_cast<uint4*>(a16 + g) = *reinterpret_cast<const uint4*>(o);
}

// ---------------- prep: generic f32 -> bf16 ----------------
__global__ __launch_bounds__(256) void k_cvt(const float* __restrict__ src, u16* __restrict__ dst){
  int g = (blockIdx.x * 256 + threadIdx.x) * 8;
  float4 v0 = *reinterpret_cast<const float4*>(src + g);
  float4 v1 = *reinterpret_cast<const float4*>(src + g + 4);
  u16 o[8];
  o[0]=f2bf(v0.x); o[1]=f2bf(v0.y); o[2]=f2bf(v0.z); o[3]=f2bf(v0.w);
  o[4]=f2bf(v1.x); o[5]=f2bf(v1.y); o[6]=f2bf(v1.z); o[7]=f2bf(v1.w);
  *reinterpret_cast<uint4*>(dst + g) = *reinterpret_cast<const uint4*>(o);
}

// ---------------- init: h0 -> bf16 parity0, zero barrier counters ----------------
__global__ __launch_bounds__(256) void k_init16(
    const float* __restrict__ h0, u16* __restrict__ h16, u32* __restrict__ bar)
{
  int g = (blockIdx.x * 256 + threadIdx.x) * 8;      // < 2*B*H = 32768
  float4 v0 = *reinterpret_cast<const float4*>(h0 + g);
  float4 v1 = *reinterpret_cast<const float4*>(h0 + g + 4);
  u16 o[8];
  o[0]=f2bf(v0.x); o[1]=f2bf(v0.y); o[2]=f2bf(v0.z); o[3]=f2bf(v0.w);
  o[4]=f2bf(v1.x); o[5]=f2bf(v1.y); o[6]=f2bf(v1.z); o[7]=f2bf(v1.w);
  *reinterpret_cast<uint4*>(h16 + g) = *reinterpret_cast<const uint4*>(o);
  if (blockIdx.x == 0 && threadIdx.x < 2) bar[threadIdx.x] = 0u;
}

// ---------------- phase A: xw = A16 @ W16^T + bias  (bf16 MFMA, 128x128 tile) ----------------
__global__ __launch_bounds__(256) void k_gemm_xw16(
    const u16* __restrict__ a16, const u16* __restrict__ w16ih,
    const float* __restrict__ b_ih_f, const float* __restrict__ b_hh_f,
    const float* __restrict__ b_ih_b, const float* __restrict__ b_hh_b,
    u16* __restrict__ xw)
{
  int dir = blockIdx.z;
  int n0 = blockIdx.x * 128;
  int m0 = blockIdx.y * 128;
  const u16* Wp = w16ih + (size_t)dir * G4 * E;
  const float* bi = dir ? b_ih_b : b_ih_f;
  const float* bh = dir ? b_hh_b : b_hh_f;
  int tid = threadIdx.x;

  __shared__ u16 As[128 * 32];
  __shared__ u16 Bs[128 * 32];

  int l  = tid & 63;
  int wid = tid >> 6;
  int wr = wid >> 1, wc = wid & 1;       // 2x2 wave grid, each wave 64x64
  int lr = l & 15, lh = l >> 4;
  int swzr = (lh ^ (lr & 3)) << 3;

  f32x4 acc[4][4];
  #pragma unroll
  for (int i = 0; i < 4; ++i)
    #pragma unroll
    for (int j = 0; j < 4; ++j)
      acc[i][j] = (f32x4){0.f, 0.f, 0.f, 0.f};

  for (int kt = 0; kt < E; kt += 32){
    __syncthreads();
    #pragma unroll
    for (int it = 0; it < 2; ++it){
      int u = it * 256 + tid;            // 0..511 (16B units)
      int row = u >> 2, c = u & 3;
      int sw = (c ^ (row & 3)) << 3;
      *reinterpret_cast<uint4*>(&As[row * 32 + sw]) =
        *reinterpret_cast<const uint4*>(a16 + (size_t)(m0 + row) * E + kt + c * 8);
      *reinterpret_cast<uint4*>(&Bs[row * 32 + sw]) =
        *reinterpret_cast<const uint4*>(Wp + (size_t)(n0 + row) * E + kt + c * 8);
    }
    __syncthreads();
    bf16x8 a[4], b[4];
    #pragma unroll
    for (int mi = 0; mi < 4; ++mi)
      a[mi] = *reinterpret_cast<const bf16x8*>(&As[(wr * 64 + mi * 16 + lr) * 32 + swzr]);
    #pragma unroll
    for (int ni = 0; ni < 4; ++ni)
      b[ni] = *reinterpret_cast<const bf16x8*>(&Bs[(wc * 64 + ni * 16 + lr) * 32 + swzr]);
    #pragma unroll
    for (int mi = 0; mi < 4; ++mi)
      #pragma unroll
      for (int ni = 0; ni < 4; ++ni)
        acc[mi][ni] = __builtin_amdgcn_mfma_f32_16x16x32_bf16(a[mi], b[ni], acc[mi][ni], 0, 0, 0);
  }

  #pragma unroll
  for (int ni = 0; ni < 4; ++ni){
    int n = n0 + wc * 64 + ni * 16 + lr;
    float bias = bi[n] + bh[n];
    #pragma unroll
    for (int mi = 0; mi < 4; ++mi){
      #pragma unroll
      for (int r = 0; r < 4; ++r){
        int m = m0 + wr * 64 + mi * 16 + lh * 4 + r;
        xw[((size_t)dir * 8192 + m) * G4 + n] = f2bf(acc[mi][ni][r] + bias);
      }
    }
  }
}

// ---------------- persistent bidirectional LSTM recurrence ----------------
// 64 blocks: dir = bx>>5 (32 blocks per dir), j0 = (bx&31)*16 (16 h-dims per block).
// w_hh slice resident in LDS; c in registers; h exchanged through the device
// coherence point via RELAXED agent-scope atomics (sc1: bypass non-coherent L1/L2
// -> NO cache-wide fences, L2 stays warm for xw). Barrier: per-dir monotonic
// counter, RELEASE add + RELAXED poll (no buffer_inv).
__device__ __forceinline__ void grid_bar(u32* cnt, u32 target){
  // drain this thread's sc1 stores to the coherence point, then block-sync
  asm volatile("s_waitcnt vmcnt(0)" ::: "memory");
  __syncthreads();
  if (threadIdx.x == 0){
    __hip_atomic_fetch_add(cnt, 1u, __ATOMIC_RELEASE, __HIP_MEMORY_SCOPE_AGENT);
    while (__hip_atomic_load(cnt, __ATOMIC_RELAXED, __HIP_MEMORY_SCOPE_AGENT) < target)
      __builtin_amdgcn_s_sleep(2);
  }
  __syncthreads();
}

__global__ __launch_bounds__(256) void k_lstm_all(
    const u16* __restrict__ w16hh, const u16* __restrict__ xw,
    u16* __restrict__ h16,              // [2 parity][2 dir][32][512] bf16
    const float* __restrict__ c0,       // [2][32][512] f32
    u16* __restrict__ hseq,             // [2 dir][8192][512] bf16
    u32* __restrict__ bar)              // [2] per-dir counters (zeroed each launch)
{
  __shared__ u16   w_s[64 * 512];       // 64 KB, XOR-swizzled
  __shared__ float gate_s[4][32][17];   // [gate][batch][jj]

  int bx  = blockIdx.x;
  int dir = bx >> 5;
  int j0  = (bx & 31) << 4;
  int tid = threadIdx.x;

  // ---- stage w_hh slice into LDS once (rows r = g*16+jj -> global row g*512+j0+jj) ----
  #pragma unroll
  for (int i = 0; i < 16; ++i){
    int u = i * 256 + tid;              // 0..4095 (16B units)
    int r = u >> 6, ku = u & 63;
    int g = r >> 4, jj = r & 15;
    const u16* src = w16hh + (size_t)dir * (G4 * H) + (size_t)((g << 9) + j0 + jj) * H + ku * 8;
    int idx = (r * 512 + ku * 8) ^ ((r & 7) << 3);
    *reinterpret_cast<uint4*>(&w_s[idx]) = *reinterpret_cast<const uint4*>(src);
  }

  int l  = tid & 63;
  int wid = tid >> 6;
  int wr = wid >> 1;                    // batch half (0,1)
  int wc = wid & 1;                     // gate pair (0: i,f  1: g,o)
  int lr = l & 15, lh = l >> 4;

  int r0 = wc * 32 + lr;                // W_lds row for gate 2*wc
  int r1 = r0 + 16;                     // gate 2*wc+1
  int base0 = r0 * 512 + lh * 8;
  int base1 = r1 * 512 + lh * 8;
  int sw = (lr & 7) << 3;               // (r0&7)==(r1&7)==(lr&7)

  // per-lane h-row pointer (u64 units), row = wr*16+lr, dims start lh*8
  int arow_u16 = ((wr << 4) + lr) * H + (lh << 3);

  // epilogue mapping: thread -> (batch eb, 2 adjacent jj)
  int eb = tid >> 3;
  int ej = (tid & 7) << 1;
  float c_reg[2];
  c_reg[0] = c0[((size_t)dir * B + eb) * H + j0 + ej];
  c_reg[1] = c0[((size_t)dir * B + eb) * H + j0 + ej + 1];

  __syncthreads();

  for (int t = 0; t < S_LEN; ++t){
    int s_eff = dir ? (S_LEN - 1 - t) : t;

    // prefetch xw for the epilogue (independent of h)
    const u16* xwp = xw + ((size_t)dir * 8192 + (size_t)s_eff * B + eb) * G4 + j0 + ej;
    u32 xi = *reinterpret_cast<const u32*>(xwp);
    u32 xf = *reinterpret_cast<const u32*>(xwp + 512);
    u32 xg = *reinterpret_cast<const u32*>(xwp + 1024);
    u32 xo = *reinterpret_cast<const u32*>(xwp + 1536);

    // ---- batch-issue the 32 coherent (sc1) h loads: pipelined, waitcnt at use ----
    const u64* ap64 = reinterpret_cast<const u64*>(
        h16 + (size_t)(t & 1) * (2 * B * H) + (size_t)dir * (B * H) + arow_u16);
    u64 qa[32];
    #pragma unroll
    for (int kt = 0; kt < 16; ++kt){
      qa[2*kt]   = __hip_atomic_load(ap64 + kt * 8,     __ATOMIC_RELAXED, __HIP_MEMORY_SCOPE_AGENT);
      qa[2*kt+1] = __hip_atomic_load(ap64 + kt * 8 + 1, __ATOMIC_RELAXED, __HIP_MEMORY_SCOPE_AGENT);
    }

    // gates = h @ W^T for this block's 64 gate-rows
    f32x4 acc0 = {0.f,0.f,0.f,0.f}, acc1 = {0.f,0.f,0.f,0.f};
    #pragma unroll
    for (int kt = 0; kt < 16; ++kt){
      union { u64 q[2]; bf16x8 v; } ua;
      ua.q[0] = qa[2*kt]; ua.q[1] = qa[2*kt+1];
      bf16x8 b0 = *reinterpret_cast<const bf16x8*>(&w_s[(base0 + kt * 32) ^ sw]);
      bf16x8 b1 = *reinterpret_cast<const bf16x8*>(&w_s[(base1 + kt * 32) ^ sw]);
      acc0 = __builtin_amdgcn_mfma_f32_16x16x32_bf16(ua.v, b0, acc0, 0, 0, 0);
      acc1 = __builtin_amdgcn_mfma_f32_16x16x32_bf16(ua.v, b1, acc1, 0, 0, 0);
    }
    #pragma unroll
    for (int r = 0; r < 4; ++r){
      gate_s[wc * 2 + 0][(wr << 4) + (lh << 2) + r][lr] = acc0[r];
      gate_s[wc * 2 + 1][(wr << 4) + (lh << 2) + r][lr] = acc1[r];
    }
    __syncthreads();

    // epilogue: c/h update for (eb, ej..ej+1)
    float hv[2];
    #pragma unroll
    for (int e = 0; e < 2; ++e){
      float iv = gate_s[0][eb][ej + e] + bf2f(e ? (u16)(xi >> 16) : (u16)(xi & 0xffff));
      float fv = gate_s[1][eb][ej + e] + bf2f(e ? (u16)(xf >> 16) : (u16)(xf & 0xffff));
      float gv = gate_s[2][eb][ej + e] + bf2f(e ? (u16)(xg >> 16) : (u16)(xg & 0xffff));
      float ov = gate_s[3][eb][ej + e] + bf2f(e ? (u16)(xo >> 16) : (u16)(xo & 0xffff));
      float cn = sigf(fv) * c_reg[e] + sigf(iv) * tanh_fast(gv);
      hv[e] = sigf(ov) * tanh_fast(cn);
      c_reg[e] = cn;
    }
    u32 hpack = (u32)f2bf(hv[0]) | ((u32)f2bf(hv[1]) << 16);
    size_t hoff = ((size_t)dir * B + eb) * H + j0 + ej;   // u16 units, even
    // coherent (sc1) store of the new h pair
    __hip_atomic_store(
        reinterpret_cast<u32*>(h16) + (((size_t)((t + 1) & 1) * (2 * B * H) + hoff) >> 1),
        hpack, __ATOMIC_RELAXED, __HIP_MEMORY_SCOPE_AGENT);
    // hseq is only consumed after this kernel ends: plain store
    *reinterpret_cast<u32*>(hseq + ((size_t)dir * 8192 + (size_t)s_eff * B + eb) * H + j0 + ej) = hpack;

    if (t < S_LEN - 1)
      grid_bar(&bar[dir], 32u * (u32)(t + 1));
  }
}

// ---------------- phase C: feats[b][s][t] = [hf;hb] . w_out[t] + b_out[t] ----------------
__global__ __launch_bounds__(256) void k_feats2(
    const u16* __restrict__ hseq, const float* __restrict__ w_out,
    const float* __restrict__ b_out, float* __restrict__ feats)
{
  __shared__ float row[32][1028];
  int blk = blockIdx.x;
  int tid = threadIdx.x;
  const u16* hf16 = hseq;
  const u16* hb16 = hseq + (size_t)8192 * H;

  #pragma unroll
  for (int it = 0; it < 16; ++it){
    int u = it * 256 + tid;
    int flat = u * 8;
    int i = flat >> 10, d = flat & 1023;
    int m = blk * 32 + i;
    const u16* src = (d < 512) ? (hf16 + (size_t)m * H + d) : (hb16 + (size_t)m * H + d - 512);
    uint4 v = *reinterpret_cast<const uint4*>(src);
    float* dst = &row[i][d];
    dst[0] = bf2f((u16)(v.x & 0xffff)); dst[1] = bf2f((u16)(v.x >> 16));
    dst[2] = bf2f((u16)(v.y & 0xffff)); dst[3] = bf2f((u16)(v.y >> 16));
    dst[4] = bf2f((u16)(v.z & 0xffff)); dst[5] = bf2f((u16)(v.z >> 16));
    dst[6] = bf2f((u16)(v.w & 0xffff)); dst[7] = bf2f((u16)(v.w >> 16));
  }
  __syncthreads();

  int i = tid >> 3, tg = tid & 7;
  const float* w0 = w_out + (size_t)((tg + 0  < T_TAGS) ? tg + 0  : 0) * 1024;
  const float* w1 = w_out + (size_t)((tg + 8  < T_TAGS) ? tg + 8  : 0) * 1024;
  const float* w2 = w_out + (size_t)((tg + 16 < T_TAGS) ? tg + 16 : 0) * 1024;
  const float* w3 = w_out + (size_t)((tg + 24 < T_TAGS) ? tg + 24 : 0) * 1024;
  float s0 = 0.f, s1 = 0.f, s2 = 0.f, s3 = 0.f;
  #pragma unroll 4
  for (int k4 = 0; k4 < 256; ++k4){
    float4 rv = *reinterpret_cast<const float4*>(&row[i][k4 * 4]);
    float4 a = *reinterpret_cast<const float4*>(w0 + k4 * 4);
    float4 b = *reinterpret_cast<const float4*>(w1 + k4 * 4);
    float4 c = *reinterpret_cast<const float4*>(w2 + k4 * 4);
    float4 d = *reinterpret_cast<const float4*>(w3 + k4 * 4);
    s0 = fmaf(a.x,rv.x,s0); s0 = fmaf(a.y,rv.y,s0); s0 = fmaf(a.z,rv.z,s0); s0 = fmaf(a.w,rv.w,s0);
    s1 = fmaf(b.x,rv.x,s1); s1 = fmaf(b.y,rv.y,s1); s1 = fmaf(b.z,rv.z,s1); s1 = fmaf(b.w,rv.w,s1);
    s2 = fmaf(c.x,rv.x,s2); s2 = fmaf(c.y,rv.y,s2); s2 = fmaf(c.z,rv.z,s2); s2 = fmaf(c.w,rv.w,s2);
    s3 = fmaf(d.x,rv.x,s3); s3 = fmaf(d.y,rv.y,s3); s3 = fmaf(d.z,rv.z,s3); s3 = fmaf(d.w,rv.w,s3);
  }
  int m = blk * 32 + i;
  int s = m >> 5, b = m & 31;
  float* fp = feats + ((size_t)b * S_LEN + s) * T_TAGS;
  float sums[4] = {s0, s1, s2, s3};
  #pragma unroll
  for (int q = 0; q < 4; ++q){
    int tt = tg + q * 8;
    if (tt < T_TAGS) fp[tt] = sums[q] + b_out[tt];
  }
}

// ---------------- phase D: CRF, one wave per batch element, register-resident ----------------
__global__ __launch_bounds__(64) void k_crf2(
    const float* __restrict__ feats, const float* __restrict__ trans,
    const int* __restrict__ tags, float* __restrict__ scores)
{
  int b = blockIdx.x;
  int l = threadIdx.x;

  float trr[T_TAGS];
  #pragma unroll
  for (int j = 0; j < T_TAGS; ++j)
    trr[j] = (l < T_TAGS) ? trans[l * T_TAGS + j] : -1e30f;

  float fv = (l == START_TAG) ? 0.f : -10000.f;
  const float* fb = feats + (size_t)b * S_LEN * T_TAGS;

  for (int s = 0; s < S_LEN; ++s){
    float feat = (l < T_TAGS) ? fb[s * T_TAGS + l] : 0.f;
    float v[T_TAGS];
    float m = -1e30f;
    #pragma unroll
    for (int j = 0; j < T_TAGS; ++j){
      float fvj = __shfl(fv, j);
      v[j] = fvj + trr[j];
      m = fmaxf(m, v[j]);
    }
    float sum = 0.f;
    #pragma unroll
    for (int j = 0; j < T_TAGS; ++j) sum += __expf(v[j] - m);
    fv = feat + m + __logf(sum);
  }

  float fin = (l < T_TAGS) ? fv + trans[STOP_TAG * T_TAGS + l] : -1e30f;
  float mm = fin;
  #pragma unroll
  for (int o = 32; o > 0; o >>= 1) mm = fmaxf(mm, __shfl_xor(mm, o));
  float e = (l < T_TAGS) ? __expf(fin - mm) : 0.f;
  #pragma unroll
  for (int o = 32; o > 0; o >>= 1) e += __shfl_xor(e, o);
  float fsc = mm + __logf(e);

  float g = 0.f;
  #pragma unroll
  for (int it = 0; it < 4; ++it){
    int s = it * 64 + l;
    int nxt = tags[s * B + b];
    int prv = s ? tags[(s - 1) * B + b] : START_TAG;
    g += trans[nxt * T_TAGS + prv] + fb[s * T_TAGS + nxt];
  }
  #pragma unroll
  for (int o = 32; o > 0; o >>= 1) g += __shfl_down(g, o);
  if (l == 0){
    int last = tags[(S_LEN - 1) * B + b];
    g += trans[STOP_TAG * T_TAGS + last];
    scores[b] = fsc - g;
  }
}

__global__ void k_final(const float* __restrict__ scores, float* __restrict__ out){
  int tid = threadIdx.x;
  float v = (tid < B) ? scores[tid] : 0.f;
  #pragma unroll
  for (int o = 32; o > 0; o >>= 1) v += __shfl_down(v, o);
  if (tid == 0) out[0] = v;
}

// ---------------- host ----------------
extern "C" void kernel_launch(void* const* d_in, const int* in_sizes, int n_in,
                              void* d_out, int out_size, void* d_ws, size_t ws_size,
                              hipStream_t stream)
{
  const int*   sent   = (const int*)d_in[0];
  const int*   tags   = (const int*)d_in[1];
  const float* emb    = (const float*)d_in[2];
  const float* w_ih_f = (const float*)d_in[3];
  const float* w_hh_f = (const float*)d_in[4];
  const float* b_ih_f = (const float*)d_in[5];
  const float* b_hh_f = (const float*)d_in[6];
  const float* w_ih_b = (const float*)d_in[7];
  const float* w_hh_b = (const float*)d_in[8];
  const float* b_ih_b = (const float*)d_in[9];
  const float* b_hh_b = (const float*)d_in[10];
  const float* w_out  = (const float*)d_in[11];
  const float* b_out  = (const float*)d_in[12];
  const float* trans  = (const float*)d_in[13];
  const float* h0     = (const float*)d_in[14];
  const float* c0     = (const float*)d_in[15];

  // ws layout (bytes)
  const size_t OFF_XW   = 0;            // bf16 [2][8192][2048] = 64 MiB
  const size_t OFF_A16  = 67108864;     // bf16 [8192][512]     = 8 MiB
  const size_t OFF_WIH  = 75497472;     // bf16 [2][2048][512]  = 4 MiB
  const size_t OFF_WHH  = 79691776;     // bf16 [2][2048][512]  = 4 MiB
  const size_t OFF_HSEQ = 83886080;     // bf16 [2][8192][512]  = 16 MiB
  const size_t OFF_H16  = 100663296;    // bf16 [2 parity][2][32][512] = 128 KiB
  const size_t OFF_FEATS= 100794368;    // f32  [32][256][30]   = 960 KiB
  const size_t OFF_SC   = 101777408;    // f32  [32]
  const size_t OFF_BAR  = 101777536;    // u32  [2]
  const size_t NEED     = 101777664;
  if (ws_size < NEED) return;

  char* ws = (char*)d_ws;
  u16*   xw     = (u16*)(ws + OFF_XW);
  u16*   a16    = (u16*)(ws + OFF_A16);
  u16*   w16ih  = (u16*)(ws + OFF_WIH);
  u16*   w16hh  = (u16*)(ws + OFF_WHH);
  u16*   hseq   = (u16*)(ws + OFF_HSEQ);
  u16*   h16    = (u16*)(ws + OFF_H16);
  float* feats  = (float*)(ws + OFF_FEATS);
  float* scores = (float*)(ws + OFF_SC);
  u32*   bar    = (u32*)(ws + OFF_BAR);

  k_prep_a<<<2048, 256, 0, stream>>>(sent, emb, a16);
  k_cvt<<<512, 256, 0, stream>>>(w_ih_f, w16ih);
  k_cvt<<<512, 256, 0, stream>>>(w_ih_b, w16ih + (size_t)G4 * E);
  k_cvt<<<512, 256, 0, stream>>>(w_hh_f, w16hh);
  k_cvt<<<512, 256, 0, stream>>>(w_hh_b, w16hh + (size_t)G4 * H);
  k_init16<<<16, 256, 0, stream>>>(h0, h16, bar);

  k_gemm_xw16<<<dim3(G4 / 128, 8192 / 128, 2), 256, 0, stream>>>(
      a16, w16ih, b_ih_f, b_hh_f, b_ih_b, b_hh_b, xw);

  k_lstm_all<<<64, 256, 0, stream>>>(w16hh, xw, h16, c0, hseq, bar);

  k_feats2<<<256, 256, 0, stream>>>(hseq, w_out, b_out, feats);
  k_crf2<<<B, 64, 0, stream>>>(feats, trans, tags, scores);
  k_final<<<1, 64, 0, stream>>>(scores, (float*)d_out);
}

// Round 5
// 1859.312 us; speedup vs baseline: 1.3863x; 1.1045x over previous
//
#include <hip/hip_runtime.h>
#include <hip/hip_bf16.h>
#include <math.h>

#define S_LEN 256
#define B 32
#define E 512
#define H 512
#define G4 2048          // 4*H
#define T_TAGS 30
#define START_TAG 28
#define STOP_TAG 29

typedef unsigned short u16;
typedef unsigned int   u32;
typedef unsigned long long u64;
typedef __attribute__((ext_vector_type(8))) short bf16x8;
typedef __attribute__((ext_vector_type(4))) float f32x4;

__device__ __forceinline__ float bf2f(u16 u){
  u32 x = ((u32)u) << 16;
  return __uint_as_float(x);
}
__device__ __forceinline__ u16 f2bf(float f){
  u32 x = __float_as_uint(f);
  u32 r = (x + 0x7fffu + ((x >> 16) & 1u)) >> 16;
  return (u16)r;
}
__device__ __forceinline__ float sigf(float x){
  return 1.0f / (1.0f + __expf(-x));
}
__device__ __forceinline__ float tanh_fast(float x){
  return 1.0f - 2.0f / (__expf(2.0f * x) + 1.0f);
}

// ---------------- prep: gather + f32->bf16 for A (emb rows) ----------------
__global__ __launch_bounds__(256) void k_prep_a(
    const int* __restrict__ sent, const float* __restrict__ emb,
    u16* __restrict__ a16)
{
  int g = (blockIdx.x * 256 + threadIdx.x) * 8;      // < 8192*512
  int token = g >> 9, k = g & 511;
  const float* src = emb + (size_t)sent[token] * E + k;
  float4 v0 = *reinterpret_cast<const float4*>(src);
  float4 v1 = *reinterpret_cast<const float4*>(src + 4);
  u16 o[8];
  o[0]=f2bf(v0.x); o[1]=f2bf(v0.y); o[2]=f2bf(v0.z); o[3]=f2bf(v0.w);
  o[4]=f2bf(v1.x); o[5]=f2bf(v1.y); o[6]=f2bf(v1.z); o[7]=f2bf(v1.w);
  *reinterpret_cast<uint4*>(a16 + g) = *reinterpret_cast<const uint4*>(o);
}

// ---------------- prep: generic f32 -> bf16 ----------------
__global__ __launch_bounds__(256) void k_cvt(const float* __restrict__ src, u16* __restrict__ dst){
  int g = (blockIdx.x * 256 + threadIdx.x) * 8;
  float4 v0 = *reinterpret_cast<const float4*>(src + g);
  float4 v1 = *reinterpret_cast<const float4*>(src + g + 4);
  u16 o[8];
  o[0]=f2bf(v0.x); o[1]=f2bf(v0.y); o[2]=f2bf(v0.z); o[3]=f2bf(v0.w);
  o[4]=f2bf(v1.x); o[5]=f2bf(v1.y); o[6]=f2bf(v1.z); o[7]=f2bf(v1.w);
  *reinterpret_cast<uint4*>(dst + g) = *reinterpret_cast<const uint4*>(o);
}

// ---------------- init: h0 -> bf16 parity0, zero barrier flags ----------------
__global__ __launch_bounds__(256) void k_init16(
    const float* __restrict__ h0, u16* __restrict__ h16, u32* __restrict__ bar)
{
  int g = (blockIdx.x * 256 + threadIdx.x) * 8;      // < 2*B*H = 32768
  float4 v0 = *reinterpret_cast<const float4*>(h0 + g);
  float4 v1 = *reinterpret_cast<const float4*>(h0 + g + 4);
  u16 o[8];
  o[0]=f2bf(v0.x); o[1]=f2bf(v0.y); o[2]=f2bf(v0.z); o[3]=f2bf(v0.w);
  o[4]=f2bf(v1.x); o[5]=f2bf(v1.y); o[6]=f2bf(v1.z); o[7]=f2bf(v1.w);
  *reinterpret_cast<uint4*>(h16 + g) = *reinterpret_cast<const uint4*>(o);
  if (blockIdx.x == 0 && threadIdx.x < 64) bar[threadIdx.x] = 0u;
}

// ---------------- phase A: xw = A16 @ W16^T + bias  (bf16 MFMA, 128x128 tile) ----------------
__global__ __launch_bounds__(256) void k_gemm_xw16(
    const u16* __restrict__ a16, const u16* __restrict__ w16ih,
    const float* __restrict__ b_ih_f, const float* __restrict__ b_hh_f,
    const float* __restrict__ b_ih_b, const float* __restrict__ b_hh_b,
    u16* __restrict__ xw)
{
  int dir = blockIdx.z;
  int n0 = blockIdx.x * 128;
  int m0 = blockIdx.y * 128;
  const u16* Wp = w16ih + (size_t)dir * G4 * E;
  const float* bi = dir ? b_ih_b : b_ih_f;
  const float* bh = dir ? b_hh_b : b_hh_f;
  int tid = threadIdx.x;

  __shared__ u16 As[128 * 32];
  __shared__ u16 Bs[128 * 32];

  int l  = tid & 63;
  int wid = tid >> 6;
  int wr = wid >> 1, wc = wid & 1;       // 2x2 wave grid, each wave 64x64
  int lr = l & 15, lh = l >> 4;
  int swzr = (lh ^ (lr & 3)) << 3;

  f32x4 acc[4][4];
  #pragma unroll
  for (int i = 0; i < 4; ++i)
    #pragma unroll
    for (int j = 0; j < 4; ++j)
      acc[i][j] = (f32x4){0.f, 0.f, 0.f, 0.f};

  for (int kt = 0; kt < E; kt += 32){
    __syncthreads();
    #pragma unroll
    for (int it = 0; it < 2; ++it){
      int u = it * 256 + tid;            // 0..511 (16B units)
      int row = u >> 2, c = u & 3;
      int sw = (c ^ (row & 3)) << 3;
      *reinterpret_cast<uint4*>(&As[row * 32 + sw]) =
        *reinterpret_cast<const uint4*>(a16 + (size_t)(m0 + row) * E + kt + c * 8);
      *reinterpret_cast<uint4*>(&Bs[row * 32 + sw]) =
        *reinterpret_cast<const uint4*>(Wp + (size_t)(n0 + row) * E + kt + c * 8);
    }
    __syncthreads();
    bf16x8 a[4], b[4];
    #pragma unroll
    for (int mi = 0; mi < 4; ++mi)
      a[mi] = *reinterpret_cast<const bf16x8*>(&As[(wr * 64 + mi * 16 + lr) * 32 + swzr]);
    #pragma unroll
    for (int ni = 0; ni < 4; ++ni)
      b[ni] = *reinterpret_cast<const bf16x8*>(&Bs[(wc * 64 + ni * 16 + lr) * 32 + swzr]);
    #pragma unroll
    for (int mi = 0; mi < 4; ++mi)
      #pragma unroll
      for (int ni = 0; ni < 4; ++ni)
        acc[mi][ni] = __builtin_amdgcn_mfma_f32_16x16x32_bf16(a[mi], b[ni], acc[mi][ni], 0, 0, 0);
  }

  #pragma unroll
  for (int ni = 0; ni < 4; ++ni){
    int n = n0 + wc * 64 + ni * 16 + lr;
    float bias = bi[n] + bh[n];
    #pragma unroll
    for (int mi = 0; mi < 4; ++mi){
      #pragma unroll
      for (int r = 0; r < 4; ++r){
        int m = m0 + wr * 64 + mi * 16 + lh * 4 + r;
        xw[((size_t)dir * 8192 + m) * G4 + n] = f2bf(acc[mi][ni][r] + bias);
      }
    }
  }
}

// ---------------- persistent bidirectional LSTM recurrence ----------------
// 64 blocks: dir = bx>>5 (32 blocks per dir), j0 = (bx&31)*16 (16 h-dims per block).
// w_hh slice resident in LDS; c in registers; h exchanged through the device
// coherence point via RELAXED agent-scope (sc1) loads/stores.
// Sync: RMW-FREE single-writer flag barrier. Block (dir,slice) owns flag
// bar[dir*32+slice]; publishes flag=t+1 after its h[t+1] stores drain
// (s_waitcnt vmcnt(0)). Consumers poll all 32 flags (one 128B line) with
// plain relaxed loads — no atomic contention, no cache-wide fences.
__global__ __launch_bounds__(256) void k_lstm_all(
    const u16* __restrict__ w16hh, const u16* __restrict__ xw,
    u16* __restrict__ h16,              // [2 parity][2 dir][32][512] bf16
    const float* __restrict__ c0,       // [2][32][512] f32
    u16* __restrict__ hseq,             // [2 dir][8192][512] bf16
    u32* __restrict__ bar)              // [2][32] per-block flags (zeroed each launch)
{
  __shared__ u16   w_s[64 * 512];       // 64 KB, XOR-swizzled
  __shared__ float gate_s[4][32][17];   // [gate][batch][jj]

  int bx    = blockIdx.x;
  int dir   = bx >> 5;
  int slice = bx & 31;
  int j0    = slice << 4;
  int tid   = threadIdx.x;

  // ---- stage w_hh slice into LDS once (rows r = g*16+jj -> global row g*512+j0+jj) ----
  #pragma unroll
  for (int i = 0; i < 16; ++i){
    int u = i * 256 + tid;              // 0..4095 (16B units)
    int r = u >> 6, ku = u & 63;
    int g = r >> 4, jj = r & 15;
    const u16* src = w16hh + (size_t)dir * (G4 * H) + (size_t)((g << 9) + j0 + jj) * H + ku * 8;
    int idx = (r * 512 + ku * 8) ^ ((r & 7) << 3);
    *reinterpret_cast<uint4*>(&w_s[idx]) = *reinterpret_cast<const uint4*>(src);
  }

  int l  = tid & 63;
  int wid = tid >> 6;
  int wr = wid >> 1;                    // batch half (0,1)
  int wc = wid & 1;                     // gate pair (0: i,f  1: g,o)
  int lr = l & 15, lh = l >> 4;

  int r0 = wc * 32 + lr;                // W_lds row for gate 2*wc
  int r1 = r0 + 16;                     // gate 2*wc+1
  int base0 = r0 * 512 + lh * 8;
  int base1 = r1 * 512 + lh * 8;
  int sw = (lr & 7) << 3;               // (r0&7)==(r1&7)==(lr&7)

  // per-lane h-row offset (u16 units), row = wr*16+lr, dims start lh*8
  int arow_u16 = ((wr << 4) + lr) * H + (lh << 3);

  // epilogue mapping: thread -> (batch eb, 2 adjacent jj)
  int eb = tid >> 3;
  int ej = (tid & 7) << 1;
  float c_reg[2];
  c_reg[0] = c0[((size_t)dir * B + eb) * H + j0 + ej];
  c_reg[1] = c0[((size_t)dir * B + eb) * H + j0 + ej + 1];

  const u32* fl = bar + dir * 32;

  __syncthreads();

  for (int t = 0; t < S_LEN; ++t){
    int s_eff = dir ? (S_LEN - 1 - t) : t;

    // 1. prefetch xw for the epilogue (independent of h) — overlaps the wait
    const u16* xwp = xw + ((size_t)dir * 8192 + (size_t)s_eff * B + eb) * G4 + j0 + ej;
    u32 xi = *reinterpret_cast<const u32*>(xwp);
    u32 xf = *reinterpret_cast<const u32*>(xwp + 512);
    u32 xg = *reinterpret_cast<const u32*>(xwp + 1024);
    u32 xo = *reinterpret_cast<const u32*>(xwp + 1536);

    // 2. wait for all 32 producer flags of this dir to reach t (RMW-free)
    if (t > 0){
      if (tid < 32){
        while (__hip_atomic_load(fl + tid, __ATOMIC_RELAXED, __HIP_MEMORY_SCOPE_AGENT) < (u32)t)
          __builtin_amdgcn_s_sleep(1);
      }
      __syncthreads();
    }

    // 3. batch-issue the coherent (sc1) h loads
    const u64* ap64 = reinterpret_cast<const u64*>(
        h16 + (size_t)(t & 1) * (2 * B * H) + (size_t)dir * (B * H) + arow_u16);
    u64 qa[32];
    #pragma unroll
    for (int kt = 0; kt < 16; ++kt){
      qa[2*kt]   = __hip_atomic_load(ap64 + kt * 8,     __ATOMIC_RELAXED, __HIP_MEMORY_SCOPE_AGENT);
      qa[2*kt+1] = __hip_atomic_load(ap64 + kt * 8 + 1, __ATOMIC_RELAXED, __HIP_MEMORY_SCOPE_AGENT);
    }

    // 4. gates = h @ W^T for this block's 64 gate-rows
    f32x4 acc0 = {0.f,0.f,0.f,0.f}, acc1 = {0.f,0.f,0.f,0.f};
    #pragma unroll
    for (int kt = 0; kt < 16; ++kt){
      union { u64 q[2]; bf16x8 v; } ua;
      ua.q[0] = qa[2*kt]; ua.q[1] = qa[2*kt+1];
      bf16x8 b0 = *reinterpret_cast<const bf16x8*>(&w_s[(base0 + kt * 32) ^ sw]);
      bf16x8 b1 = *reinterpret_cast<const bf16x8*>(&w_s[(base1 + kt * 32) ^ sw]);
      acc0 = __builtin_amdgcn_mfma_f32_16x16x32_bf16(ua.v, b0, acc0, 0, 0, 0);
      acc1 = __builtin_amdgcn_mfma_f32_16x16x32_bf16(ua.v, b1, acc1, 0, 0, 0);
    }
    #pragma unroll
    for (int r = 0; r < 4; ++r){
      gate_s[wc * 2 + 0][(wr << 4) + (lh << 2) + r][lr] = acc0[r];
      gate_s[wc * 2 + 1][(wr << 4) + (lh << 2) + r][lr] = acc1[r];
    }
    __syncthreads();

    // 5. epilogue: c/h update for (eb, ej..ej+1)
    float hv[2];
    #pragma unroll
    for (int e = 0; e < 2; ++e){
      float iv = gate_s[0][eb][ej + e] + bf2f(e ? (u16)(xi >> 16) : (u16)(xi & 0xffff));
      float fv = gate_s[1][eb][ej + e] + bf2f(e ? (u16)(xf >> 16) : (u16)(xf & 0xffff));
      float gv = gate_s[2][eb][ej + e] + bf2f(e ? (u16)(xg >> 16) : (u16)(xg & 0xffff));
      float ov = gate_s[3][eb][ej + e] + bf2f(e ? (u16)(xo >> 16) : (u16)(xo & 0xffff));
      float cn = sigf(fv) * c_reg[e] + sigf(iv) * tanh_fast(gv);
      hv[e] = sigf(ov) * tanh_fast(cn);
      c_reg[e] = cn;
    }
    u32 hpack = (u32)f2bf(hv[0]) | ((u32)f2bf(hv[1]) << 16);
    size_t hoff = ((size_t)dir * B + eb) * H + j0 + ej;   // u16 units, even
    // coherent (sc1) store of the new h pair into parity buffer (t+1)&1
    __hip_atomic_store(
        reinterpret_cast<u32*>(h16) + (((size_t)((t + 1) & 1) * (2 * B * H) + hoff) >> 1),
        hpack, __ATOMIC_RELAXED, __HIP_MEMORY_SCOPE_AGENT);
    // hseq is only consumed after this kernel ends: plain store
    *reinterpret_cast<u32*>(hseq + ((size_t)dir * 8192 + (size_t)s_eff * B + eb) * H + j0 + ej) = hpack;

    // 6. publish: drain our stores to the coherence point, then set our flag
    asm volatile("s_waitcnt vmcnt(0)" ::: "memory");
    __syncthreads();
    if (tid == 0)
      __hip_atomic_store(bar + dir * 32 + slice, (u32)(t + 1),
                         __ATOMIC_RELAXED, __HIP_MEMORY_SCOPE_AGENT);
  }
}

// ---------------- phase C: feats[b][s][t] = [hf;hb] . w_out[t] + b_out[t] ----------------
__global__ __launch_bounds__(256) void k_feats2(
    const u16* __restrict__ hseq, const float* __restrict__ w_out,
    const float* __restrict__ b_out, float* __restrict__ feats)
{
  __shared__ float row[32][1028];
  int blk = blockIdx.x;
  int tid = threadIdx.x;
  const u16* hf16 = hseq;
  const u16* hb16 = hseq + (size_t)8192 * H;

  #pragma unroll
  for (int it = 0; it < 16; ++it){
    int u = it * 256 + tid;
    int flat = u * 8;
    int i = flat >> 10, d = flat & 1023;
    int m = blk * 32 + i;
    const u16* src = (d < 512) ? (hf16 + (size_t)m * H + d) : (hb16 + (size_t)m * H + d - 512);
    uint4 v = *reinterpret_cast<const uint4*>(src);
    float* dst = &row[i][d];
    dst[0] = bf2f((u16)(v.x & 0xffff)); dst[1] = bf2f((u16)(v.x >> 16));
    dst[2] = bf2f((u16)(v.y & 0xffff)); dst[3] = bf2f((u16)(v.y >> 16));
    dst[4] = bf2f((u16)(v.z & 0xffff)); dst[5] = bf2f((u16)(v.z >> 16));
    dst[6] = bf2f((u16)(v.w & 0xffff)); dst[7] = bf2f((u16)(v.w >> 16));
  }
  __syncthreads();

  int i = tid >> 3, tg = tid & 7;
  const float* w0 = w_out + (size_t)((tg + 0  < T_TAGS) ? tg + 0  : 0) * 1024;
  const float* w1 = w_out + (size_t)((tg + 8  < T_TAGS) ? tg + 8  : 0) * 1024;
  const float* w2 = w_out + (size_t)((tg + 16 < T_TAGS) ? tg + 16 : 0) * 1024;
  const float* w3 = w_out + (size_t)((tg + 24 < T_TAGS) ? tg + 24 : 0) * 1024;
  float s0 = 0.f, s1 = 0.f, s2 = 0.f, s3 = 0.f;
  #pragma unroll 4
  for (int k4 = 0; k4 < 256; ++k4){
    float4 rv = *reinterpret_cast<const float4*>(&row[i][k4 * 4]);
    float4 a = *reinterpret_cast<const float4*>(w0 + k4 * 4);
    float4 b = *reinterpret_cast<const float4*>(w1 + k4 * 4);
    float4 c = *reinterpret_cast<const float4*>(w2 + k4 * 4);
    float4 d = *reinterpret_cast<const float4*>(w3 + k4 * 4);
    s0 = fmaf(a.x,rv.x,s0); s0 = fmaf(a.y,rv.y,s0); s0 = fmaf(a.z,rv.z,s0); s0 = fmaf(a.w,rv.w,s0);
    s1 = fmaf(b.x,rv.x,s1); s1 = fmaf(b.y,rv.y,s1); s1 = fmaf(b.z,rv.z,s1); s1 = fmaf(b.w,rv.w,s1);
    s2 = fmaf(c.x,rv.x,s2); s2 = fmaf(c.y,rv.y,s2); s2 = fmaf(c.z,rv.z,s2); s2 = fmaf(c.w,rv.w,s2);
    s3 = fmaf(d.x,rv.x,s3); s3 = fmaf(d.y,rv.y,s3); s3 = fmaf(d.z,rv.z,s3); s3 = fmaf(d.w,rv.w,s3);
  }
  int m = blk * 32 + i;
  int s = m >> 5, b = m & 31;
  float* fp = feats + ((size_t)b * S_LEN + s) * T_TAGS;
  float sums[4] = {s0, s1, s2, s3};
  #pragma unroll
  for (int q = 0; q < 4; ++q){
    int tt = tg + q * 8;
    if (tt < T_TAGS) fp[tt] = sums[q] + b_out[tt];
  }
}

// ---------------- phase D: CRF, one wave per batch element, register-resident ----------------
__global__ __launch_bounds__(64) void k_crf2(
    const float* __restrict__ feats, const float* __restrict__ trans,
    const int* __restrict__ tags, float* __restrict__ scores)
{
  int b = blockIdx.x;
  int l = threadIdx.x;

  float trr[T_TAGS];
  #pragma unroll
  for (int j = 0; j < T_TAGS; ++j)
    trr[j] = (l < T_TAGS) ? trans[l * T_TAGS + j] : -1e30f;

  float fv = (l == START_TAG) ? 0.f : -10000.f;
  const float* fb = feats + (size_t)b * S_LEN * T_TAGS;

  for (int s = 0; s < S_LEN; ++s){
    float feat = (l < T_TAGS) ? fb[s * T_TAGS + l] : 0.f;
    float v[T_TAGS];
    float m = -1e30f;
    #pragma unroll
    for (int j = 0; j < T_TAGS; ++j){
      float fvj = __shfl(fv, j);
      v[j] = fvj + trr[j];
      m = fmaxf(m, v[j]);
    }
    float sum = 0.f;
    #pragma unroll
    for (int j = 0; j < T_TAGS; ++j) sum += __expf(v[j] - m);
    fv = feat + m + __logf(sum);
  }

  float fin = (l < T_TAGS) ? fv + trans[STOP_TAG * T_TAGS + l] : -1e30f;
  float mm = fin;
  #pragma unroll
  for (int o = 32; o > 0; o >>= 1) mm = fmaxf(mm, __shfl_xor(mm, o));
  float e = (l < T_TAGS) ? __expf(fin - mm) : 0.f;
  #pragma unroll
  for (int o = 32; o > 0; o >>= 1) e += __shfl_xor(e, o);
  float fsc = mm + __logf(e);

  float g = 0.f;
  #pragma unroll
  for (int it = 0; it < 4; ++it){
    int s = it * 64 + l;
    int nxt = tags[s * B + b];
    int prv = s ? tags[(s - 1) * B + b] : START_TAG;
    g += trans[nxt * T_TAGS + prv] + fb[s * T_TAGS + nxt];
  }
  #pragma unroll
  for (int o = 32; o > 0; o >>= 1) g += __shfl_down(g, o);
  if (l == 0){
    int last = tags[(S_LEN - 1) * B + b];
    g += trans[STOP_TAG * T_TAGS + last];
    scores[b] = fsc - g;
  }
}

__global__ void k_final(const float* __restrict__ scores, float* __restrict__ out){
  int tid = threadIdx.x;
  float v = (tid < B) ? scores[tid] : 0.f;
  #pragma unroll
  for (int o = 32; o > 0; o >>= 1) v += __shfl_down(v, o);
  if (tid == 0) out[0] = v;
}

// ---------------- host ----------------
extern "C" void kernel_launch(void* const* d_in, const int* in_sizes, int n_in,
                              void* d_out, int out_size, void* d_ws, size_t ws_size,
                              hipStream_t stream)
{
  const int*   sent   = (const int*)d_in[0];
  const int*   tags   = (const int*)d_in[1];
  const float* emb    = (const float*)d_in[2];
  const float* w_ih_f = (const float*)d_in[3];
  const float* w_hh_f = (const float*)d_in[4];
  const float* b_ih_f = (const float*)d_in[5];
  const float* b_hh_f = (const float*)d_in[6];
  const float* w_ih_b = (const float*)d_in[7];
  const float* w_hh_b = (const float*)d_in[8];
  const float* b_ih_b = (const float*)d_in[9];
  const float* b_hh_b = (const float*)d_in[10];
  const float* w_out  = (const float*)d_in[11];
  const float* b_out  = (const float*)d_in[12];
  const float* trans  = (const float*)d_in[13];
  const float* h0     = (const float*)d_in[14];
  const float* c0     = (const float*)d_in[15];

  // ws layout (bytes)
  const size_t OFF_XW   = 0;            // bf16 [2][8192][2048] = 64 MiB
  const size_t OFF_A16  = 67108864;     // bf16 [8192][512]     = 8 MiB
  const size_t OFF_WIH  = 75497472;     // bf16 [2][2048][512]  = 4 MiB
  const size_t OFF_WHH  = 79691776;     // bf16 [2][2048][512]  = 4 MiB
  const size_t OFF_HSEQ = 83886080;     // bf16 [2][8192][512]  = 16 MiB
  const size_t OFF_H16  = 100663296;    // bf16 [2 parity][2][32][512] = 128 KiB
  const size_t OFF_FEATS= 100794368;    // f32  [32][256][30]   = 960 KiB
  const size_t OFF_SC   = 101777408;    // f32  [32]
  const size_t OFF_BAR  = 101777536;    // u32  [2][32] = 256 B
  const size_t NEED     = 101777792;
  if (ws_size < NEED) return;

  char* ws = (char*)d_ws;
  u16*   xw     = (u16*)(ws + OFF_XW);
  u16*   a16    = (u16*)(ws + OFF_A16);
  u16*   w16ih  = (u16*)(ws + OFF_WIH);
  u16*   w16hh  = (u16*)(ws + OFF_WHH);
  u16*   hseq   = (u16*)(ws + OFF_HSEQ);
  u16*   h16    = (u16*)(ws + OFF_H16);
  float* feats  = (float*)(ws + OFF_FEATS);
  float* scores = (float*)(ws + OFF_SC);
  u32*   bar    = (u32*)(ws + OFF_BAR);

  k_prep_a<<<2048, 256, 0, stream>>>(sent, emb, a16);
  k_cvt<<<512, 256, 0, stream>>>(w_ih_f, w16ih);
  k_cvt<<<512, 256, 0, stream>>>(w_ih_b, w16ih + (size_t)G4 * E);
  k_cvt<<<512, 256, 0, stream>>>(w_hh_f, w16hh);
  k_cvt<<<512, 256, 0, stream>>>(w_hh_b, w16hh + (size_t)G4 * H);
  k_init16<<<16, 256, 0, stream>>>(h0, h16, bar);

  k_gemm_xw16<<<dim3(G4 / 128, 8192 / 128, 2), 256, 0, stream>>>(
      a16, w16ih, b_ih_f, b_hh_f, b_ih_b, b_hh_b, xw);

  k_lstm_all<<<64, 256, 0, stream>>>(w16hh, xw, h16, c0, hseq, bar);

  k_feats2<<<256, 256, 0, stream>>>(hseq, w_out, b_out, feats);
  k_crf2<<<B, 64, 0, stream>>>(feats, trans, tags, scores);
  k_final<<<1, 64, 0, stream>>>(scores, (float*)d_out);
}